// Round 8
// baseline (296.555 us; speedup 1.0000x reference)
//
#include <hip/hip_runtime.h>
#include <hip/hip_bf16.h>

#define B_   4
#define L_   1024
#define D_   1280
#define H_   20
#define DH_  64
#define BH_  (B_*H_)     // 80
#define L2_  (2*L_)      // 2048
#define ALPHA_ 0.48f
// Q prescale: 0.125 (score scale) * log2(e) -> scores in log2 domain, exp = v_exp_f32
#define QSCALE_ 0.180336880f

typedef __attribute__((ext_vector_type(8))) short short8;
typedef __attribute__((ext_vector_type(4))) float float4v;

__device__ __forceinline__ float exp2_fast(float x) {
    float r;
    asm volatile("v_exp_f32 %0, %1" : "=v"(r) : "v"(x));
    return r;
}

__device__ __forceinline__ ushort f2bf(float f) {
    union { float f; unsigned int i; } v; v.f = f;
    unsigned int i = v.i;
    unsigned int r = i + 0x7FFF + ((i >> 16) & 1);  // RNE
    return (ushort)(r >> 16);
}
__device__ __forceinline__ short8 pack8(float4 f0, float4 f1) {
    short8 o;
    o[0] = (short)f2bf(f0.x); o[1] = (short)f2bf(f0.y);
    o[2] = (short)f2bf(f0.z); o[3] = (short)f2bf(f0.w);
    o[4] = (short)f2bf(f1.x); o[5] = (short)f2bf(f1.y);
    o[6] = (short)f2bf(f1.z); o[7] = (short)f2bf(f1.w);
    return o;
}
// pack 4 f32 -> 4 bf16 (RNE) and store as one 8-byte write
__device__ __forceinline__ void pack4_store(ushort* dst, float a, float b, float c, float d) {
    union { __hip_bfloat162 h; unsigned int u; } x, y;
    x.h = __float22bfloat162_rn(make_float2(a, b));
    y.h = __float22bfloat162_rn(make_float2(c, d));
    uint2 v; v.x = x.u; v.y = y.u;
    *(uint2*)dst = v;
}

// async global->LDS, 16 B per lane; dest = wave-uniform base + lane*16
__device__ __forceinline__ void async16(const void* g, void* l) {
    __builtin_amdgcn_global_load_lds(
        (__attribute__((address_space(1))) void*)g,
        (__attribute__((address_space(3))) void*)l, 16, 0, 0);
}

// ---------------- fused prep (inputs f32) -------------------------------------------
// K/V stored in flash-staging tile order so flash's global_load_lds is coalesced:
//   Kc tile  [bh][kt]      : elem (c*64 + kv)*8 + e  = bf16(K[kt*64+kv][c*8+e])
//   Vc tile  [bh][kt 0..31]: elem (cc*64 + d)*8 + e  = bf16((a)V[kt*64+rho(cc,e)][d])
// rho(cc,e) = (cc>>2)*32 + (e>>2)*16 + (cc&3)*4 + (e&3): V rows permuted relative to
// K rows so that flash's P fragment is lane-local (in-register P, no LDS round-trip).
// Softmax is permutation-invariant over kv, so this is exact.
// bi <  1600 : Wt[z][c][r] = bf16(w_z[r][c])          (weight transposes)
// bi <  2880 : Vc bg tiles (kt 16..31) from Vbg, alpha-scaled
// bi <  5440 : Xb  = bf16(X)
// bi <  6720 : Kc bg tiles from Kbg (unscaled; alpha applied on log2-scores in flash)
__global__ __launch_bounds__(256) void prep(
    const float* __restrict__ w0, const float* __restrict__ w1,
    const float* __restrict__ w2, const float* __restrict__ w3,
    ushort* __restrict__ Wt,
    const float* __restrict__ Vbg, ushort* __restrict__ Vt,
    const float* __restrict__ X, ushort* __restrict__ Xb,
    const float* __restrict__ Kbg, ushort* __restrict__ Kcv) {
    int bi = blockIdx.x, tid = threadIdx.x;
    __shared__ __align__(16) ushort t[64 * 72];
    if (bi < 2880) {
        bool doScale = (bi >= 1600);
        const float* src; int srcld; long sbase;
        ushort* dst = nullptr; int dstld = 0; long dbase = 0;  // W path
        ushort* vout = nullptr;                                // V path
        if (bi < 1600) {
            int z = bi / 400, t4 = bi % 400;
            int by = t4 / 20, bx = t4 % 20;
            const float* srcs[4] = {w0, w1, w2, w3};
            src = srcs[z]; srcld = D_; dstld = D_;
            sbase = (long)(by * 64) * D_ + bx * 64;
            dst = Wt + (long)z * D_ * D_;
            dbase = (long)(bx * 64) * D_ + by * 64;
        } else {
            int j = bi - 1600;          // 0..1279
            int bh = j >> 4, kt = j & 15;
            src = Vbg; srcld = DH_;
            sbase = ((long)bh * L_ + kt * 64) * DH_;
            vout = Vt + (((long)bh * 32 + 16 + kt) << 12);
        }
        int ldr = tid >> 3, ldc = (tid & 7) * 8;
#pragma unroll
        for (int i = 0; i < 2; i++) {
            int y = ldr + 32 * i;
            long idx = sbase + (long)y * srcld + ldc;
            float4 f0 = *(const float4*)&src[idx];
            float4 f1 = *(const float4*)&src[idx + 4];
            if (doScale) {
                f0.x *= ALPHA_; f0.y *= ALPHA_; f0.z *= ALPHA_; f0.w *= ALPHA_;
                f1.x *= ALPHA_; f1.y *= ALPHA_; f1.z *= ALPHA_; f1.w *= ALPHA_;
            }
            *(short8*)&t[y * 72 + ldc] = pack8(f0, f1);
        }
        __syncthreads();
        if (bi < 1600) {
            int r8 = (tid & 7) * 8, c0 = tid >> 3;   // coalesced: wave covers 8 c-rows
#pragma unroll
            for (int i = 0; i < 2; i++) {
                int c = c0 + i * 32;
                short8 o;
#pragma unroll
                for (int j2 = 0; j2 < 8; j2++) o[j2] = (short)t[(r8 + j2) * 72 + c];
                *(short8*)&dst[dbase + (long)c * dstld + r8] = o;
            }
        } else {
            // Vc tile (rho-permuted): out chunk jj = cc*64 + d, elem e <- t[rho][d]
#pragma unroll
            for (int i = 0; i < 2; i++) {
                int jj = i * 256 + tid;
                int cc = jj >> 6, d2 = jj & 63;
                int rb = (cc >> 2) * 32 + (cc & 3) * 4;
                short8 o;
#pragma unroll
                for (int e = 0; e < 8; e++)
                    o[e] = (short)t[(rb + (e >> 2) * 16 + (e & 3)) * 72 + d2];
                *(short8*)&vout[(long)jj * 8] = o;
            }
        }
    } else if (bi < 5440) {
        long i = ((long)(bi - 2880) * 256 + tid) * 8;
        *(short8*)&Xb[i] = pack8(*(const float4*)&X[i], *(const float4*)&X[i + 4]);
    } else {
        // Kc bg tile permute: 16B-chunk reorder via LDS (coalesced both sides)
        int j2 = bi - 5440;             // 0..1279
        int bh = j2 >> 4, kt = j2 & 15;
        const float* src = Kbg + ((long)bh * L_ + kt * 64) * DH_;
#pragma unroll
        for (int i = 0; i < 2; i++) {
            int r = i * 256 + tid;      // chunk (kv, cd): coalesced 32B f32 reads
            int kv = r >> 3, cd = r & 7;
            long idx = (long)kv * 64 + cd * 8;
            *(short8*)&t[kv * 72 + cd * 8] =
                pack8(*(const float4*)&src[idx], *(const float4*)&src[idx + 4]);
        }
        __syncthreads();
        ushort* outp = Kcv + (((long)bh * 16 + kt) << 12);
#pragma unroll
        for (int i = 0; i < 2; i++) {
            int jj = i * 256 + tid;     // out chunk jj = c*64 + kv: coalesced writes
            int c = jj >> 6, kv = jj & 63;
            *(short8*)&outp[(long)jj * 8] = *(const short8*)&t[kv * 72 + c * 8];
        }
    }
}

// ---------------- GEMM (bf16): C[m][n] = sum_k A[m][k]*Bt[n][k], K=1280 --------------
// R14 schedule (kept): counted-vmcnt + raw barrier pair; prefetch flies across
// barriers, hidden under the whole next iteration.
// mode 0: scatter -> Qp (x QSCALE_), Kc tiles, Vc tiles (rho-permuted)
// mode 1: Out(f32) = acc + bo[n]
template<int BMt, int BNt, int WROWS, int WCOLS>
__global__ __launch_bounds__(256) void gemm_tpl(
    const ushort* __restrict__ A, const ushort* __restrict__ Bt,
    ushort* __restrict__ Qp, ushort* __restrict__ Kp, ushort* __restrict__ Vt,
    float* __restrict__ Out, const float* __restrict__ bo, int mode) {
    constexpr int MI = BMt / WROWS / 16;
    constexpr int NI = BNt / WCOLS / 16;
    constexpr int ASZ = BMt * 32, BSZ = BNt * 32;
    constexpr int RB = 1280 / BNt;  // blocks per 1280-wide output region
    constexpr int NLD = BMt / 64 + BNt / 64;  // async loads per wave per stage
    __shared__ __align__(16) ushort Al[2 * ASZ];
    __shared__ __align__(16) ushort Bl[2 * BSZ];
    int tid = threadIdx.x;
    int bx = blockIdx.x, by = blockIdx.y;
    int w = tid >> 6, lane = tid & 63, l15 = lane & 15, quad = lane >> 4;
    int wm = (w / WCOLS) * (BMt / WROWS);
    int wn = (w % WCOLS) * (BNt / WCOLS);
    float4v acc[MI][NI] = {};
    const int K = 1280;
    constexpr int NK = 40;
    const ushort* Arow = A + (long)by * BMt * K + (tid >> 2) * K + (tid & 3) * 8;
    const ushort* Brow = Bt + (long)bx * BNt * K + (tid >> 2) * K + (tid & 3) * 8;

    auto stage = [&](int ki, int b) {
#pragma unroll
        for (int i = 0; i < BMt / 64; i++)
            async16(Arow + (long)i * 64 * K + ki * 32, &Al[b * ASZ + (i * 4 + w) * 512]);
#pragma unroll
        for (int i = 0; i < BNt / 64; i++)
            async16(Brow + (long)i * 64 * K + ki * 32, &Bl[b * BSZ + (i * 4 + w) * 512]);
    };

    stage(0, 0);
    for (int ki = 0; ki < NK; ki++) {
        int cur = ki & 1;
        if (ki + 1 < NK) {
            stage(ki + 1, 1 - cur);
            if constexpr (NLD == 4) asm volatile("s_waitcnt vmcnt(4)" ::: "memory");
            else if constexpr (NLD == 3) asm volatile("s_waitcnt vmcnt(3)" ::: "memory");
            else asm volatile("s_waitcnt vmcnt(0)" ::: "memory");
        } else {
            asm volatile("s_waitcnt vmcnt(0)" ::: "memory");
        }
        __builtin_amdgcn_sched_barrier(0);
        __builtin_amdgcn_s_barrier();     // all waves' cur loads retired
        __builtin_amdgcn_sched_barrier(0);
        short8 av[MI], bv[NI];
#pragma unroll
        for (int mi = 0; mi < MI; mi++)
            av[mi] = *(const short8*)&Al[cur * ASZ + (wm + mi * 16 + l15) * 32 + quad * 8];
#pragma unroll
        for (int ni = 0; ni < NI; ni++)
            bv[ni] = *(const short8*)&Bl[cur * BSZ + (wn + ni * 16 + l15) * 32 + quad * 8];
#pragma unroll
        for (int mi = 0; mi < MI; mi++)
#pragma unroll
            for (int ni = 0; ni < NI; ni++)
                acc[mi][ni] = __builtin_amdgcn_mfma_f32_16x16x32_bf16(av[mi], bv[ni], acc[mi][ni], 0, 0, 0);
        __builtin_amdgcn_sched_barrier(0);
        __builtin_amdgcn_s_barrier();     // all waves done reading cur buffer
    }

    if (mode == 0) {
        int which = bx / RB;
#pragma unroll
        for (int mi = 0; mi < MI; mi++) {
            int m0 = by * BMt + wm + mi * 16 + quad * 4;
            int b = m0 >> 10, l0 = m0 & 1023;
#pragma unroll
            for (int ni = 0; ni < NI; ni++) {
                int n = bx * BNt + wn + ni * 16 + l15;
                int np = n - which * 1280;
                int h = np >> 6, dh = np & 63;
                if (which == 0) {
#pragma unroll
                    for (int r = 0; r < 4; r++)
                        Qp[((long)(b * H_ + h) * L_ + l0 + r) * DH_ + dh] =
                            f2bf(acc[mi][ni][r] * QSCALE_);
                } else if (which == 1) {
                    // Kc tile: elem ((bh*16+kt)*8 + dh/8)*512 + (kv&63)*8 + dh&7
                    long kb = ((((long)(b * H_ + h) * 16 + (l0 >> 6)) * 8 + (dh >> 3)) * 64
                               + (l0 & 63)) * 8 + (dh & 7);
#pragma unroll
                    for (int r = 0; r < 4; r++)
                        Kp[kb + r * 8] = f2bf(acc[mi][ni][r]);
                } else {
                    // Vc tile, rho-permuted rows: j = kv&63 ->
                    // cc = ((j>>5)<<2)|((j>>2)&3), elem base = ((j>>4)&1)<<2
                    int j = l0 & 63;
                    int cc = ((j >> 5) << 2) | ((j >> 2) & 3);
                    int eb = ((j >> 4) & 1) << 2;
                    pack4_store(&Vt[((((long)(b * H_ + h) * 32 + (l0 >> 6)) * 8
                                      + cc) * 64 + dh) * 8 + eb],
                                acc[mi][ni][0], acc[mi][ni][1],
                                acc[mi][ni][2], acc[mi][ni][3]);
                }
            }
        }
    } else {
#pragma unroll
        for (int mi = 0; mi < MI; mi++) {
            int mloc = wm + mi * 16 + quad * 4;
#pragma unroll
            for (int ni = 0; ni < NI; ni++) {
                int nloc = wn + ni * 16 + l15;
#pragma unroll
                for (int r = 0; r < 4; r++) {
                    int m = by * BMt + mloc + r;
                    int n = bx * BNt + nloc;
                    Out[(long)m * D_ + n] = acc[mi][ni][r] + bo[n];
                }
            }
        }
    }
}

// ---------------- flash attention: q-split, FAT iterations (kv=128/barrier) ---------
// R15: R7 proved flash isn't staging-latency-bound; counters (VGPR=44!, MfmaUtil 22,
// VALUBusy 49, occ 28%) convict the 32 thin lockstep iterations: the compiler
// register-minimized each into a near-serial chain, and per-iter fixed cost (2
// barriers + LDS latency + chain ramp) dominates. Now each iteration stages and
// consumes TWO 64-kv tiles: 16 iters x {16 QK-MFMA, 32 exp, 16 PV-MFMA}/wave --
// 8 independent s4 accs + 32 independent exps force wide ILP (VGPR ~125), fixed
// cost paid half as often. LDS 64KB -> exactly 2 blocks/CU, 1280 = 5x256 balanced.
// FP summation order bit-identical (halves iterate in old kt order; bg at iter 8).
__global__ __launch_bounds__(256) void flash_attn(
    const ushort* __restrict__ Qp, const ushort* __restrict__ Kp,
    const ushort* __restrict__ Kbg, const ushort* __restrict__ Vt,
    ushort* __restrict__ Ctx) {
    __shared__ __align__(16) ushort Kl[2 * 8192], Vl[2 * 8192];
    int tid = threadIdx.x;
    int w = tid >> 6, lane = tid & 63, l15 = lane & 15, quad = lane >> 4;
    int bi = blockIdx.x;
    int bh = (bi & 7) * 10 + ((bi >> 3) % 10);   // same-bh blocks share bi&7 (XCD)
    int qt = bi / 80;                            // 0..15: 64-row q tile

    // Q fragments: wave w owns q rows qt*64 + w*16 .. +16 (loop-invariant)
    short8 aq[2];
    const ushort* Qb = Qp + ((long)bh * L_ + qt * 64 + w * 16) * DH_;
#pragma unroll
    for (int ks = 0; ks < 2; ks++)
        aq[ks] = *(const short8*)&Qb[l15 * DH_ + ks * 32 + quad * 8];

    float rs = 0.f;
    float4v O[4] = {};

    auto stage = [&](int it, int b) {  // stages old-kt = 2it, 2it+1 (8 loads/wave)
#pragma unroll
        for (int half = 0; half < 2; half++) {
            int kt = 2 * it + half;
            const ushort* Ksrc = (kt < 16)
                ? Kp  + (((long)bh * 16 + kt) << 12)
                : Kbg + (((long)bh * 16 + (kt - 16)) << 12);
            const ushort* Vsrc = Vt + (((long)bh * 32 + kt) << 12);
#pragma unroll
            for (int i = 0; i < 2; i++) {
                int c = w * 2 + i;
                async16(&Ksrc[c * 512 + lane * 8], &Kl[b * 8192 + half * 4096 + c * 512]);
                async16(&Vsrc[c * 512 + lane * 8], &Vl[b * 8192 + half * 4096 + c * 512]);
            }
        }
    };

    stage(0, 0);
    for (int it = 0; it < 16; it++) {
        int cur = it & 1;
        if (it + 1 < 16) {
            stage(it + 1, 1 - cur);
            asm volatile("s_waitcnt vmcnt(8)" ::: "memory");  // it's 8 done, it+1's fly
        } else {
            asm volatile("s_waitcnt vmcnt(0)" ::: "memory");
        }
        __builtin_amdgcn_sched_barrier(0);
        __builtin_amdgcn_s_barrier();     // collective: cur buffer fully staged
        __builtin_amdgcn_sched_barrier(0);
        bool bg = (it >= 8);
        // S^T = MFMA(A=K, B=Q), both halves: 8 independent accumulators
        float4v s4[8] = {};
#pragma unroll
        for (int half = 0; half < 2; half++)
#pragma unroll
            for (int ks = 0; ks < 2; ks++) {
                short8 bk[4];
#pragma unroll
                for (int nt = 0; nt < 4; nt++)
                    bk[nt] = *(const short8*)&Kl[cur * 8192 + half * 4096
                                                 + (ks * 4 + quad) * 512 + (nt * 16 + l15) * 8];
#pragma unroll
                for (int nt = 0; nt < 4; nt++)
                    s4[half * 4 + nt] = __builtin_amdgcn_mfma_f32_16x16x32_bf16(
                        bk[nt], aq[ks], s4[half * 4 + nt], 0, 0, 0);
            }
        // p = 2^s (alpha on bg log2-scores); rs lane-local; 32 independent exps
        float p[8][4];
#pragma unroll
        for (int j = 0; j < 8; j++)
#pragma unroll
            for (int r = 0; r < 4; r++) {
                float sv = s4[j][r];
                if (bg) sv *= ALPHA_;
                p[j][r] = exp2_fast(sv);
                rs += p[j][r];
            }
        // O^T += MFMA(A=V^T, B=P) per half; rho-permuted V rows keep P lane-local
#pragma unroll
        for (int half = 0; half < 2; half++) {
            short8 ap[2];
#pragma unroll
            for (int ks = 0; ks < 2; ks++) {
                union { __hip_bfloat162 h[4]; short8 s; } u;
                const int j0 = half * 4 + 2 * ks, j1 = j0 + 1;
                u.h[0] = __float22bfloat162_rn(make_float2(p[j0][0], p[j0][1]));
                u.h[1] = __float22bfloat162_rn(make_float2(p[j0][2], p[j0][3]));
                u.h[2] = __float22bfloat162_rn(make_float2(p[j1][0], p[j1][1]));
                u.h[3] = __float22bfloat162_rn(make_float2(p[j1][2], p[j1][3]));
                ap[ks] = u.s;
            }
#pragma unroll
            for (int ks = 0; ks < 2; ks++) {
                short8 bv[4];
#pragma unroll
                for (int nt = 0; nt < 4; nt++)
                    bv[nt] = *(const short8*)&Vl[cur * 8192 + half * 4096
                                                 + (ks * 4 + quad) * 512 + (nt * 16 + l15) * 8];
#pragma unroll
                for (int nt = 0; nt < 4; nt++)
                    O[nt] = __builtin_amdgcn_mfma_f32_16x16x32_bf16(
                        bv[nt], ap[ks], O[nt], 0, 0, 0);
            }
        }
        __builtin_amdgcn_sched_barrier(0);
        __builtin_amdgcn_s_barrier();     // all waves done reading cur buffer
    }
    // rs partials live across the 4 quads of each q: reduce with 2 shuffles
    float v = rs;
    v += __shfl_xor(v, 16);
    v += __shfl_xor(v, 32);
    float rcp = 1.f / v;
    int b = bh / H_, h = bh % H_;
    long l = qt * 64 + w * 16 + l15;
#pragma unroll
    for (int nt = 0; nt < 4; nt++)
        pack4_store(&Ctx[(long)(b * L_ + l) * D_ + h * DH_ + nt * 16 + quad * 4],
                    O[nt][0] * rcp, O[nt][1] * rcp,
                    O[nt][2] * rcp, O[nt][3] * rcp);
}

extern "C" void kernel_launch(void* const* d_in, const int* in_sizes, int n_in,
                              void* d_out, int out_size, void* d_ws, size_t ws_size,
                              hipStream_t stream) {
    const float* X   = (const float*)d_in[0];
    const float* Wq  = (const float*)d_in[1];
    const float* Wk  = (const float*)d_in[2];
    const float* Wv  = (const float*)d_in[3];
    const float* Wo  = (const float*)d_in[4];
    const float* bo  = (const float*)d_in[5];
    const float* Kbg = (const float*)d_in[6];
    const float* Vbg = (const float*)d_in[7];

    char* ws = (char*)d_ws;
    size_t off = 0;
    auto alloc = [&](size_t bytes) {
        void* p = ws + off;
        off = (off + bytes + 255) & ~(size_t)255;
        return p;
    };
    ushort* Wt    = (ushort*)alloc((size_t)4 * D_ * D_ * 2);     // Wq^T|Wk^T|Wv^T|Wo^T
    ushort* Qp    = (ushort*)alloc((size_t)BH_ * L_ * DH_ * 2);
    ushort* Kp    = (ushort*)alloc((size_t)BH_ * L_ * DH_ * 2);  // Kc fg tiles
    ushort* Kcv   = (ushort*)alloc((size_t)BH_ * L_ * DH_ * 2);  // Kc bg tiles
    ushort* Vt    = (ushort*)alloc((size_t)BH_ * DH_ * L2_ * 2); // Vc tiles (fg+bg)
    ushort* Xb    = (ushort*)alloc((size_t)B_ * L_ * D_ * 2);    // bf16(X); Ctx aliases
    ushort* Ctx   = Xb;  // Xb dead after QKV GEMM; flash writes Ctx afterwards
    ushort* Wqkv_t = Wt;
    ushort* Wo_t   = Wt + (size_t)3 * D_ * D_;

    prep<<<6720, 256, 0, stream>>>(Wq, Wk, Wv, Wo, Wt, Vbg, Vt, X, Xb, Kbg, Kcv);
    // QKV projection: N = 3840 (Q|K|V), M = 4096 (128x128, 960 blocks)
    gemm_tpl<128, 128, 2, 2><<<dim3(30, 32), 256, 0, stream>>>(
        Xb, Wqkv_t, Qp, Kp, Vt, nullptr, nullptr, 0);
    // attention: q-split, 1280 blocks x 256 threads, kv=128 per iteration
    flash_attn<<<dim3(1280), 256, 0, stream>>>(Qp, Kp, Kcv, Vt, Ctx);
    // output projection (64x128, 640 blocks)
    gemm_tpl<64, 128, 1, 4><<<dim3(10, 64), 256, 0, stream>>>(
        Ctx, Wo_t, nullptr, nullptr, nullptr, (float*)d_out, bo, 1);
}

// Round 10
// 291.543 us; speedup vs baseline: 1.0172x; 1.0172x over previous
//
#include <hip/hip_runtime.h>
#include <hip/hip_bf16.h>

#define B_   4
#define L_   1024
#define D_   1280
#define H_   20
#define DH_  64
#define BH_  (B_*H_)     // 80
#define L2_  (2*L_)      // 2048
#define ALPHA_ 0.48f
// Q prescale: 0.125 (score scale) * log2(e) -> scores in log2 domain, exp = v_exp_f32
#define QSCALE_ 0.180336880f

typedef __attribute__((ext_vector_type(8))) short short8;
typedef __attribute__((ext_vector_type(4))) float float4v;

__device__ __forceinline__ float exp2_fast(float x) {
    float r;
    asm volatile("v_exp_f32 %0, %1" : "=v"(r) : "v"(x));
    return r;
}

__device__ __forceinline__ ushort f2bf(float f) {
    union { float f; unsigned int i; } v; v.f = f;
    unsigned int i = v.i;
    unsigned int r = i + 0x7FFF + ((i >> 16) & 1);  // RNE
    return (ushort)(r >> 16);
}
__device__ __forceinline__ short8 pack8(float4 f0, float4 f1) {
    short8 o;
    o[0] = (short)f2bf(f0.x); o[1] = (short)f2bf(f0.y);
    o[2] = (short)f2bf(f0.z); o[3] = (short)f2bf(f0.w);
    o[4] = (short)f2bf(f1.x); o[5] = (short)f2bf(f1.y);
    o[6] = (short)f2bf(f1.z); o[7] = (short)f2bf(f1.w);
    return o;
}
// pack 4 f32 -> 4 bf16 (RNE) and store as one 8-byte write
__device__ __forceinline__ void pack4_store(ushort* dst, float a, float b, float c, float d) {
    union { __hip_bfloat162 h; unsigned int u; } x, y;
    x.h = __float22bfloat162_rn(make_float2(a, b));
    y.h = __float22bfloat162_rn(make_float2(c, d));
    uint2 v; v.x = x.u; v.y = y.u;
    *(uint2*)dst = v;
}

// async global->LDS, 16 B per lane; dest = wave-uniform base + lane*16
__device__ __forceinline__ void async16(const void* g, void* l) {
    __builtin_amdgcn_global_load_lds(
        (__attribute__((address_space(1))) void*)g,
        (__attribute__((address_space(3))) void*)l, 16, 0, 0);
}

// ---------------- fused prep (inputs f32) -------------------------------------------
// K/V stored in flash-staging tile order so flash's global_load_lds is coalesced:
//   Kc tile  [bh][kt]      : elem (c*64 + kv)*8 + e  = bf16(K[kt*64+kv][c*8+e])
//   Vc tile  [bh][kt 0..31]: elem (cc*64 + d)*8 + e  = bf16((a)V[kt*64+rho(cc,e)][d])
// rho(cc,e) = (cc>>2)*32 + (e>>2)*16 + (cc&3)*4 + (e&3): V rows permuted relative to
// K rows so that flash's P fragment is lane-local (in-register P, no LDS round-trip).
// Softmax is permutation-invariant over kv, so this is exact. Note (cc>>2) = kv>>5:
// chunks cc 0..3 hold kv 0..31, cc 4..7 hold kv 32..63 (used by kv=32 staging).
// bi <  1600 : Wt[z][c][r] = bf16(w_z[r][c])          (weight transposes)
// bi <  2880 : Vc bg tiles (kt 16..31) from Vbg, alpha-scaled
// bi <  5440 : Xb  = bf16(X)
// bi <  6720 : Kc bg tiles from Kbg (unscaled; alpha applied on log2-scores in flash)
__global__ __launch_bounds__(256) void prep(
    const float* __restrict__ w0, const float* __restrict__ w1,
    const float* __restrict__ w2, const float* __restrict__ w3,
    ushort* __restrict__ Wt,
    const float* __restrict__ Vbg, ushort* __restrict__ Vt,
    const float* __restrict__ X, ushort* __restrict__ Xb,
    const float* __restrict__ Kbg, ushort* __restrict__ Kcv) {
    int bi = blockIdx.x, tid = threadIdx.x;
    __shared__ __align__(16) ushort t[64 * 72];
    if (bi < 2880) {
        bool doScale = (bi >= 1600);
        const float* src; int srcld; long sbase;
        ushort* dst = nullptr; int dstld = 0; long dbase = 0;  // W path
        ushort* vout = nullptr;                                // V path
        if (bi < 1600) {
            int z = bi / 400, t4 = bi % 400;
            int by = t4 / 20, bx = t4 % 20;
            const float* srcs[4] = {w0, w1, w2, w3};
            src = srcs[z]; srcld = D_; dstld = D_;
            sbase = (long)(by * 64) * D_ + bx * 64;
            dst = Wt + (long)z * D_ * D_;
            dbase = (long)(bx * 64) * D_ + by * 64;
        } else {
            int j = bi - 1600;          // 0..1279
            int bh = j >> 4, kt = j & 15;
            src = Vbg; srcld = DH_;
            sbase = ((long)bh * L_ + kt * 64) * DH_;
            vout = Vt + (((long)bh * 32 + 16 + kt) << 12);
        }
        int ldr = tid >> 3, ldc = (tid & 7) * 8;
#pragma unroll
        for (int i = 0; i < 2; i++) {
            int y = ldr + 32 * i;
            long idx = sbase + (long)y * srcld + ldc;
            float4 f0 = *(const float4*)&src[idx];
            float4 f1 = *(const float4*)&src[idx + 4];
            if (doScale) {
                f0.x *= ALPHA_; f0.y *= ALPHA_; f0.z *= ALPHA_; f0.w *= ALPHA_;
                f1.x *= ALPHA_; f1.y *= ALPHA_; f1.z *= ALPHA_; f1.w *= ALPHA_;
            }
            *(short8*)&t[y * 72 + ldc] = pack8(f0, f1);
        }
        __syncthreads();
        if (bi < 1600) {
            int r8 = (tid & 7) * 8, c0 = tid >> 3;   // coalesced: wave covers 8 c-rows
#pragma unroll
            for (int i = 0; i < 2; i++) {
                int c = c0 + i * 32;
                short8 o;
#pragma unroll
                for (int j2 = 0; j2 < 8; j2++) o[j2] = (short)t[(r8 + j2) * 72 + c];
                *(short8*)&dst[dbase + (long)c * dstld + r8] = o;
            }
        } else {
            // Vc tile (rho-permuted): out chunk jj = cc*64 + d, elem e <- t[rho][d]
#pragma unroll
            for (int i = 0; i < 2; i++) {
                int jj = i * 256 + tid;
                int cc = jj >> 6, d2 = jj & 63;
                int rb = (cc >> 2) * 32 + (cc & 3) * 4;
                short8 o;
#pragma unroll
                for (int e = 0; e < 8; e++)
                    o[e] = (short)t[(rb + (e >> 2) * 16 + (e & 3)) * 72 + d2];
                *(short8*)&vout[(long)jj * 8] = o;
            }
        }
    } else if (bi < 5440) {
        long i = ((long)(bi - 2880) * 256 + tid) * 8;
        *(short8*)&Xb[i] = pack8(*(const float4*)&X[i], *(const float4*)&X[i + 4]);
    } else {
        // Kc bg tile permute: 16B-chunk reorder via LDS (coalesced both sides)
        int j2 = bi - 5440;             // 0..1279
        int bh = j2 >> 4, kt = j2 & 15;
        const float* src = Kbg + ((long)bh * L_ + kt * 64) * DH_;
#pragma unroll
        for (int i = 0; i < 2; i++) {
            int r = i * 256 + tid;      // chunk (kv, cd): coalesced 32B f32 reads
            int kv = r >> 3, cd = r & 7;
            long idx = (long)kv * 64 + cd * 8;
            *(short8*)&t[kv * 72 + cd * 8] =
                pack8(*(const float4*)&src[idx], *(const float4*)&src[idx + 4]);
        }
        __syncthreads();
        ushort* outp = Kcv + (((long)bh * 16 + kt) << 12);
#pragma unroll
        for (int i = 0; i < 2; i++) {
            int jj = i * 256 + tid;     // out chunk jj = c*64 + kv: coalesced writes
            int c = jj >> 6, kv = jj & 63;
            *(short8*)&outp[(long)jj * 8] = *(const short8*)&t[kv * 72 + c * 8];
        }
    }
}

// ---------------- GEMM (bf16): C[m][n] = sum_k A[m][k]*Bt[n][k], K=1280 --------------
// Counted-vmcnt schedule (R14, kept for GEMMs where it helped): prefetch flies
// across barriers, hidden under the whole next iteration.
// mode 0: scatter -> Qp (x QSCALE_), Kc tiles, Vc tiles (rho-permuted)
// mode 1: Out(f32) = acc + bo[n]
template<int BMt, int BNt, int WROWS, int WCOLS>
__global__ __launch_bounds__(256) void gemm_tpl(
    const ushort* __restrict__ A, const ushort* __restrict__ Bt,
    ushort* __restrict__ Qp, ushort* __restrict__ Kp, ushort* __restrict__ Vt,
    float* __restrict__ Out, const float* __restrict__ bo, int mode) {
    constexpr int MI = BMt / WROWS / 16;
    constexpr int NI = BNt / WCOLS / 16;
    constexpr int ASZ = BMt * 32, BSZ = BNt * 32;
    constexpr int RB = 1280 / BNt;  // blocks per 1280-wide output region
    constexpr int NLD = BMt / 64 + BNt / 64;  // async loads per wave per stage
    __shared__ __align__(16) ushort Al[2 * ASZ];
    __shared__ __align__(16) ushort Bl[2 * BSZ];
    int tid = threadIdx.x;
    int bx = blockIdx.x, by = blockIdx.y;
    int w = tid >> 6, lane = tid & 63, l15 = lane & 15, quad = lane >> 4;
    int wm = (w / WCOLS) * (BMt / WROWS);
    int wn = (w % WCOLS) * (BNt / WCOLS);
    float4v acc[MI][NI] = {};
    const int K = 1280;
    constexpr int NK = 40;
    const ushort* Arow = A + (long)by * BMt * K + (tid >> 2) * K + (tid & 3) * 8;
    const ushort* Brow = Bt + (long)bx * BNt * K + (tid >> 2) * K + (tid & 3) * 8;

    auto stage = [&](int ki, int b) {
#pragma unroll
        for (int i = 0; i < BMt / 64; i++)
            async16(Arow + (long)i * 64 * K + ki * 32, &Al[b * ASZ + (i * 4 + w) * 512]);
#pragma unroll
        for (int i = 0; i < BNt / 64; i++)
            async16(Brow + (long)i * 64 * K + ki * 32, &Bl[b * BSZ + (i * 4 + w) * 512]);
    };

    stage(0, 0);
    for (int ki = 0; ki < NK; ki++) {
        int cur = ki & 1;
        if (ki + 1 < NK) {
            stage(ki + 1, 1 - cur);
            if constexpr (NLD == 4) asm volatile("s_waitcnt vmcnt(4)" ::: "memory");
            else if constexpr (NLD == 3) asm volatile("s_waitcnt vmcnt(3)" ::: "memory");
            else if constexpr (NLD == 2) asm volatile("s_waitcnt vmcnt(2)" ::: "memory");
            else asm volatile("s_waitcnt vmcnt(0)" ::: "memory");
        } else {
            asm volatile("s_waitcnt vmcnt(0)" ::: "memory");
        }
        __builtin_amdgcn_sched_barrier(0);
        __builtin_amdgcn_s_barrier();     // all waves' cur loads retired
        __builtin_amdgcn_sched_barrier(0);
        short8 av[MI], bv[NI];
#pragma unroll
        for (int mi = 0; mi < MI; mi++)
            av[mi] = *(const short8*)&Al[cur * ASZ + (wm + mi * 16 + l15) * 32 + quad * 8];
#pragma unroll
        for (int ni = 0; ni < NI; ni++)
            bv[ni] = *(const short8*)&Bl[cur * BSZ + (wn + ni * 16 + l15) * 32 + quad * 8];
#pragma unroll
        for (int mi = 0; mi < MI; mi++)
#pragma unroll
            for (int ni = 0; ni < NI; ni++)
                acc[mi][ni] = __builtin_amdgcn_mfma_f32_16x16x32_bf16(av[mi], bv[ni], acc[mi][ni], 0, 0, 0);
        __builtin_amdgcn_sched_barrier(0);
        __builtin_amdgcn_s_barrier();     // all waves done reading cur buffer
    }

    if (mode == 0) {
        int which = bx / RB;
#pragma unroll
        for (int mi = 0; mi < MI; mi++) {
            int m0 = by * BMt + wm + mi * 16 + quad * 4;
            int b = m0 >> 10, l0 = m0 & 1023;
#pragma unroll
            for (int ni = 0; ni < NI; ni++) {
                int n = bx * BNt + wn + ni * 16 + l15;
                int np = n - which * 1280;
                int h = np >> 6, dh = np & 63;
                if (which == 0) {
#pragma unroll
                    for (int r = 0; r < 4; r++)
                        Qp[((long)(b * H_ + h) * L_ + l0 + r) * DH_ + dh] =
                            f2bf(acc[mi][ni][r] * QSCALE_);
                } else if (which == 1) {
                    // Kc tile: elem ((bh*16+kt)*8 + dh/8)*512 + (kv&63)*8 + dh&7
                    long kb = ((((long)(b * H_ + h) * 16 + (l0 >> 6)) * 8 + (dh >> 3)) * 64
                               + (l0 & 63)) * 8 + (dh & 7);
#pragma unroll
                    for (int r = 0; r < 4; r++)
                        Kp[kb + r * 8] = f2bf(acc[mi][ni][r]);
                } else {
                    // Vc tile, rho-permuted rows: j = kv&63 ->
                    // cc = ((j>>5)<<2)|((j>>2)&3), elem base = ((j>>4)&1)<<2
                    int j = l0 & 63;
                    int cc = ((j >> 5) << 2) | ((j >> 2) & 3);
                    int eb = ((j >> 4) & 1) << 2;
                    pack4_store(&Vt[((((long)(b * H_ + h) * 32 + (l0 >> 6)) * 8
                                      + cc) * 64 + dh) * 8 + eb],
                                acc[mi][ni][0], acc[mi][ni][1],
                                acc[mi][ni][2], acc[mi][ni][3]);
                }
            }
        }
    } else {
#pragma unroll
        for (int mi = 0; mi < MI; mi++) {
            int mloc = wm + mi * 16 + quad * 4;
#pragma unroll
            for (int ni = 0; ni < NI; ni++) {
                int nloc = wn + ni * 16 + l15;
#pragma unroll
                for (int r = 0; r < 4; r++) {
                    int m = by * BMt + mloc + r;
                    int n = bx * BNt + nloc;
                    Out[(long)m * D_ + n] = acc[mi][ni][r] + bo[n];
                }
            }
        }
    }
}

// ---------------- flash attention: q-split, kv=32 chunks, 16KB LDS ------------------
// R16: the ledger convicts LDS-per-block: flash time tracks resident blocks/CU only
// (R8 2/CU=84.5, R6 5/CU=78.2; all intra-block changes null; pipes <50% busy).
// kv=32 sub-tiles halve LDS to 16KB/block -> residency now wave-capped at 8
// blocks/CU (32 waves/CU, 1.6x R6). 64 thin iterations preserve R6's totals (thin
// proved fine in R6, fat hurt in R8). Schedule = R6's exact best (stage-at-top,
// single __syncthreads; counted-vmcnt was -3us in R7, reverted). K half-tiles are
// the h32*512B runs per dh-chunk (same 128B-granule count, coalesced); V halves are
// contiguous (rho puts kv<32 in chunks 0..3, kv>=32 in 4..7). P mapping = old ks=0
// case: ap elem e <-> p[e>>2][e&3] <-> rho(h32*4+quad, e). Summation order
// bit-identical (halves iterate in old kv order; bg boundary at it=32).
__global__ __launch_bounds__(256) void flash_attn(
    const ushort* __restrict__ Qp, const ushort* __restrict__ Kp,
    const ushort* __restrict__ Kbg, const ushort* __restrict__ Vt,
    ushort* __restrict__ Ctx) {
    __shared__ __align__(16) ushort Kl[2 * 2048], Vl[2 * 2048];
    int tid = threadIdx.x;
    int w = tid >> 6, lane = tid & 63, l15 = lane & 15, quad = lane >> 4;
    int bi = blockIdx.x;
    int bh = (bi & 7) * 10 + ((bi >> 3) % 10);   // same-bh blocks share bi&7 (XCD)
    int qt = bi / 80;                            // 0..15: 64-row q tile

    // Q fragments: wave w owns q rows qt*64 + w*16 .. +16 (loop-invariant)
    short8 aq[2];
    const ushort* Qb = Qp + ((long)bh * L_ + qt * 64 + w * 16) * DH_;
#pragma unroll
    for (int ks = 0; ks < 2; ks++)
        aq[ks] = *(const short8*)&Qb[l15 * DH_ + ks * 32 + quad * 8];

    float rs = 0.f;
    float4v O[4] = {};

    auto stage = [&](int it, int b) {  // it indexes kv-32 sub-tiles: kt=it>>1, h32=it&1
        int kt = it >> 1, h32 = it & 1;
        const ushort* Ksrc = (kt < 16)
            ? Kp  + (((long)bh * 16 + kt) << 12)
            : Kbg + (((long)bh * 16 + (kt - 16)) << 12);
        const ushort* Vsrc = Vt + (((long)bh * 32 + kt) << 12);
        // K half: lane covers c = w*2+(lane>>5), kv' = lane&31 (two 512B runs)
        async16(&Ksrc[(w * 2 + (lane >> 5)) * 512 + h32 * 256 + (lane & 31) * 8],
                &Kl[b * 2048 + w * 512]);
        // V half: chunks cc = h32*4 + w, 1KB contiguous
        async16(&Vsrc[(h32 * 4 + w) * 512 + lane * 8], &Vl[b * 2048 + w * 512]);
    };

    stage(0, 0);
    __syncthreads();
    for (int it = 0; it < 64; it++) {
        int cur = it & 1;
        if (it + 1 < 64) stage(it + 1, 1 - cur);
        bool bg = (it >= 32);
        // S^T = MFMA(A=K, B=Q): lane q = qt*64+w*16+l15, kv' = nt2*16+quad*4+r
        float4v s4[2] = {};
#pragma unroll
        for (int ks = 0; ks < 2; ks++) {
            short8 bk[2];
#pragma unroll
            for (int nt2 = 0; nt2 < 2; nt2++)
                bk[nt2] = *(const short8*)&Kl[cur * 2048 + (ks * 4 + quad) * 256
                                              + (nt2 * 16 + l15) * 8];
#pragma unroll
            for (int nt2 = 0; nt2 < 2; nt2++)
                s4[nt2] = __builtin_amdgcn_mfma_f32_16x16x32_bf16(bk[nt2], aq[ks], s4[nt2], 0, 0, 0);
        }
        // p = 2^s (alpha on bg log2-scores); rs lane-local; P in-register
        float p[2][4];
#pragma unroll
        for (int j = 0; j < 2; j++)
#pragma unroll
            for (int r = 0; r < 4; r++) {
                float sv = s4[j][r];
                if (bg) sv *= ALPHA_;
                p[j][r] = exp2_fast(sv);
                rs += p[j][r];
            }
        short8 ap;
        {
            union { __hip_bfloat162 h[4]; short8 s; } u;
            u.h[0] = __float22bfloat162_rn(make_float2(p[0][0], p[0][1]));
            u.h[1] = __float22bfloat162_rn(make_float2(p[0][2], p[0][3]));
            u.h[2] = __float22bfloat162_rn(make_float2(p[1][0], p[1][1]));
            u.h[3] = __float22bfloat162_rn(make_float2(p[1][2], p[1][3]));
            ap = u.s;
        }
        // O^T += MFMA(A=V^T, B=P): lane q = l15, d = nt*16+quad*4+r, k = kv' (32)
        short8 bv[4];
#pragma unroll
        for (int nt = 0; nt < 4; nt++)
            bv[nt] = *(const short8*)&Vl[cur * 2048 + quad * 512 + (nt * 16 + l15) * 8];
#pragma unroll
        for (int nt = 0; nt < 4; nt++)
            O[nt] = __builtin_amdgcn_mfma_f32_16x16x32_bf16(bv[nt], ap, O[nt], 0, 0, 0);
        __syncthreads();  // prefetch complete + all waves done with cur buffer
    }
    // rs partials live across the 4 quads of each q: reduce with 2 shuffles
    float v = rs;
    v += __shfl_xor(v, 16);
    v += __shfl_xor(v, 32);
    float rcp = 1.f / v;
    int b = bh / H_, h = bh % H_;
    long l = qt * 64 + w * 16 + l15;
#pragma unroll
    for (int nt = 0; nt < 4; nt++)
        pack4_store(&Ctx[(long)(b * L_ + l) * D_ + h * DH_ + nt * 16 + quad * 4],
                    O[nt][0] * rcp, O[nt][1] * rcp,
                    O[nt][2] * rcp, O[nt][3] * rcp);
}

extern "C" void kernel_launch(void* const* d_in, const int* in_sizes, int n_in,
                              void* d_out, int out_size, void* d_ws, size_t ws_size,
                              hipStream_t stream) {
    const float* X   = (const float*)d_in[0];
    const float* Wq  = (const float*)d_in[1];
    const float* Wk  = (const float*)d_in[2];
    const float* Wv  = (const float*)d_in[3];
    const float* Wo  = (const float*)d_in[4];
    const float* bo  = (const float*)d_in[5];
    const float* Kbg = (const float*)d_in[6];
    const float* Vbg = (const float*)d_in[7];

    char* ws = (char*)d_ws;
    size_t off = 0;
    auto alloc = [&](size_t bytes) {
        void* p = ws + off;
        off = (off + bytes + 255) & ~(size_t)255;
        return p;
    };
    ushort* Wt    = (ushort*)alloc((size_t)4 * D_ * D_ * 2);     // Wq^T|Wk^T|Wv^T|Wo^T
    ushort* Qp    = (ushort*)alloc((size_t)BH_ * L_ * DH_ * 2);
    ushort* Kp    = (ushort*)alloc((size_t)BH_ * L_ * DH_ * 2);  // Kc fg tiles
    ushort* Kcv   = (ushort*)alloc((size_t)BH_ * L_ * DH_ * 2);  // Kc bg tiles
    ushort* Vt    = (ushort*)alloc((size_t)BH_ * DH_ * L2_ * 2); // Vc tiles (fg+bg)
    ushort* Xb    = (ushort*)alloc((size_t)B_ * L_ * D_ * 2);    // bf16(X); Ctx aliases
    ushort* Ctx   = Xb;  // Xb dead after QKV GEMM; flash writes Ctx afterwards
    ushort* Wqkv_t = Wt;
    ushort* Wo_t   = Wt + (size_t)3 * D_ * D_;

    prep<<<6720, 256, 0, stream>>>(Wq, Wk, Wv, Wo, Wt, Vbg, Vt, X, Xb, Kbg, Kcv);
    // QKV projection: N = 3840 (Q|K|V), M = 4096 (128x128, 960 blocks)
    gemm_tpl<128, 128, 2, 2><<<dim3(30, 32), 256, 0, stream>>>(
        Xb, Wqkv_t, Qp, Kp, Vt, nullptr, nullptr, 0);
    // attention: q-split, 1280 blocks x 256 threads, kv=32 chunks, 16KB LDS
    flash_attn<<<dim3(1280), 256, 0, stream>>>(Qp, Kp, Kcv, Vt, Ctx);
    // output projection: 64x64 tile, grid (20,64) = 1280 blocks = 5/CU balanced
    gemm_tpl<64, 64, 2, 2><<<dim3(20, 64), 256, 0, stream>>>(
        Ctx, Wo_t, nullptr, nullptr, nullptr, (float*)d_out, bo, 1);
}